// Round 1
// baseline (1432.493 us; speedup 1.0000x reference)
//
#include <hip/hip_runtime.h>

#define N_NODES 50000
#define N_EDGES 1600000
#define CH 128

// ws layout (bytes):
//      0: Wt   [128*128] f32  (renormed, transposed: Wt[i][o] = W[o][i]*scale[i])
//  65536: flag [1] int        (edge_index element stride: 1 = int32, 2 = int64-low-word)
// 131072: deg  [N_NODES] int
// 393216: dinv [N_NODES] f32
// 655360: h    [N_NODES*128] f32
// total ~26.3 MB
#define WS_WT    0
#define WS_FLAG  65536
#define WS_DEG   131072
#define WS_DINV  393216
#define WS_H     655360

__global__ void k_prep(const float* __restrict__ W, const int* __restrict__ eidx,
                       float* __restrict__ Wt, int* __restrict__ flag) {
    int i = threadIdx.x;  // 128 threads
    // int64-vs-int32 detection (wave 0): for LE int64 the odd 32-bit words of
    // the first 64 values are the (zero) high halves. For int32 they are
    // random values in [0,50000) -> essentially never all zero.
    if (i < 64) {
        int v = eidx[2 * i + 1];
        unsigned long long m = __ballot(v == 0);
        if (i == 0) *flag = (m == ~0ull) ? 2 : 1;
    }
    // column i of W[out][in]: norm over out dim
    float s = 0.f;
    for (int o = 0; o < CH; ++o) { float w = W[o * CH + i]; s += w * w; }
    float scale = (s > 1.0f) ? rsqrtf(s) : 1.0f;
    for (int o = 0; o < CH; ++o) Wt[i * CH + o] = W[o * CH + i] * scale;
}

__global__ void k_deg(const int* __restrict__ eidx, const int* __restrict__ flag,
                      int* __restrict__ deg) {
    int e = blockIdx.x * blockDim.x + threadIdx.x;
    if (e >= N_EDGES) return;
    int st = *flag;
    int col = eidx[(size_t)st * (size_t)(N_EDGES + e)];
    atomicAdd(&deg[col], 1);
}

__global__ void k_dinv(const int* __restrict__ deg, float* __restrict__ dinv) {
    int n = blockIdx.x * blockDim.x + threadIdx.x;
    if (n >= N_NODES) return;
    dinv[n] = rsqrtf((float)(deg[n] + 1));  // +1 self loop; always > 0
}

// h = x @ Wn^T.  Block: 256 threads, 32 rows x 128 cols. Thread: 4x4 tile.
__global__ __launch_bounds__(256) void k_gemm(const float* __restrict__ x,
                                              const float* __restrict__ Wt,
                                              float* __restrict__ h) {
    __shared__ float xs[32 * 128];  // 16 KB
    int t = threadIdx.x;
    int base = blockIdx.x * 32;
    // stage 32 rows of x (float4-coalesced)
    #pragma unroll
    for (int j = 0; j < 4; ++j) {
        int f4 = j * 256 + t;         // float4 index in [0,1024)
        int r = f4 >> 5;              // row 0..31
        int c = (f4 & 31) * 4;        // col
        int n = base + r;
        float4 v = make_float4(0.f, 0.f, 0.f, 0.f);
        if (n < N_NODES) v = *(const float4*)&x[(size_t)n * CH + c];
        *(float4*)&xs[r * 128 + c] = v;
    }
    __syncthreads();
    int tx = t & 31;       // col group: cols 4*tx .. 4*tx+3
    int ty = t >> 5;       // row group: rows 4*ty .. 4*ty+3
    float acc[4][4] = {};
    const float* wp = Wt + 4 * tx;
    #pragma unroll 2
    for (int k = 0; k < CH; ++k) {
        float4 b = *(const float4*)&wp[k * CH];  // Wt[k][4tx..] coalesced, L1/L2-hot
        #pragma unroll
        for (int r = 0; r < 4; ++r) {
            float a = xs[(4 * ty + r) * 128 + k];  // 2 distinct rows per wave -> free
            acc[r][0] += a * b.x;
            acc[r][1] += a * b.y;
            acc[r][2] += a * b.z;
            acc[r][3] += a * b.w;
        }
    }
    #pragma unroll
    for (int r = 0; r < 4; ++r) {
        int n = base + 4 * ty + r;
        if (n < N_NODES) {
            float4 v = make_float4(acc[r][0], acc[r][1], acc[r][2], acc[r][3]);
            *(float4*)&h[(size_t)n * CH + 4 * tx] = v;
        }
    }
}

// out = h * dinv^2 + b   (self-loop message + bias; full write, no atomics)
__global__ void k_init(const float* __restrict__ h, const float* __restrict__ dinv,
                       const float* __restrict__ b, float* __restrict__ out) {
    int idx = blockIdx.x * blockDim.x + threadIdx.x;  // float4 index
    int n = idx >> 5;
    int c = (idx & 31) * 4;
    if (n >= N_NODES) return;
    float di = dinv[n];
    float s = di * di;
    float4 hv = *(const float4*)&h[(size_t)n * CH + c];
    float4 bv = *(const float4*)&b[c];
    float4 o;
    o.x = hv.x * s + bv.x;
    o.y = hv.y * s + bv.y;
    o.z = hv.z * s + bv.z;
    o.w = hv.w * s + bv.w;
    *(float4*)&out[(size_t)n * CH + c] = o;
}

// one wave per edge: lane handles 2 channels
__global__ __launch_bounds__(256) void k_scatter(const int* __restrict__ eidx,
                                                 const int* __restrict__ flag,
                                                 const float* __restrict__ dinv,
                                                 const float* __restrict__ h,
                                                 float* __restrict__ out) {
    int wid = threadIdx.x >> 6;
    int lane = threadIdx.x & 63;
    long e = (long)blockIdx.x * 4 + wid;
    if (e >= N_EDGES) return;
    int st = *flag;
    int row = eidx[(size_t)st * (size_t)e];
    int col = eidx[(size_t)st * (size_t)(N_EDGES + e)];
    float nrm = dinv[row] * dinv[col];
    float2 hv = *(const float2*)&h[(size_t)row * CH + lane * 2];
    float* op = out + (size_t)col * CH + lane * 2;
    unsafeAtomicAdd(op, hv.x * nrm);
    unsafeAtomicAdd(op + 1, hv.y * nrm);
}

extern "C" void kernel_launch(void* const* d_in, const int* in_sizes, int n_in,
                              void* d_out, int out_size, void* d_ws, size_t ws_size,
                              hipStream_t stream) {
    const float* x = (const float*)d_in[0];
    const int* eidx = (const int*)d_in[1];
    const float* W = (const float*)d_in[2];
    const float* b = (const float*)d_in[3];
    float* out = (float*)d_out;

    char* ws = (char*)d_ws;
    float* Wt   = (float*)(ws + WS_WT);
    int*   flag = (int*)(ws + WS_FLAG);
    int*   deg  = (int*)(ws + WS_DEG);
    float* dinv = (float*)(ws + WS_DINV);
    float* h    = (float*)(ws + WS_H);

    hipMemsetAsync(deg, 0, N_NODES * sizeof(int), stream);
    k_prep<<<1, 128, 0, stream>>>(W, eidx, Wt, flag);
    k_deg<<<(N_EDGES + 255) / 256, 256, 0, stream>>>(eidx, flag, deg);
    k_dinv<<<(N_NODES + 255) / 256, 256, 0, stream>>>(deg, dinv);
    k_gemm<<<(N_NODES + 31) / 32, 256, 0, stream>>>(x, Wt, h);
    k_init<<<(N_NODES * 32 + 255) / 256, 256, 0, stream>>>(h, dinv, b, out);
    k_scatter<<<(N_EDGES + 3) / 4, 256, 0, stream>>>(eidx, flag, dinv, h, out);
}

// Round 2
// 478.858 us; speedup vs baseline: 2.9915x; 2.9915x over previous
//
#include <hip/hip_runtime.h>

#define N_NODES 50000
#define N_EDGES 1600000
#define CH 128

// ws layout (bytes), total ~33 MB:
#define WS_WT      0         // Wt [128*128] f32 (renormed, transposed)
#define WS_FLAG    65536     // int: edge_index elem stride (1=int32, 2=int64 low word)
#define WS_DEG     131072    // deg [N] int
#define WS_ROWPTR  393216    // rowptr [N+1] int
#define WS_CURSOR  655360    // cursor [N] int
#define WS_DINV    917504    // dinv [N] f32
#define WS_SRC     1179648   // src [E] int   (source node of each dest-sorted edge)
#define WS_H       7684096   // hs [N*128] f32 (h pre-scaled by dinv[row])

__global__ void k_prep(const float* __restrict__ W, const int* __restrict__ eidx,
                       float* __restrict__ Wt, int* __restrict__ flag) {
    int i = threadIdx.x;  // 128 threads
    if (i < 64) {
        int v = eidx[2 * i + 1];
        unsigned long long m = __ballot(v == 0);
        if (i == 0) *flag = (m == ~0ull) ? 2 : 1;
    }
    float s = 0.f;
    for (int o = 0; o < CH; ++o) { float w = W[o * CH + i]; s += w * w; }
    float scale = (s > 1.0f) ? rsqrtf(s) : 1.0f;
    for (int o = 0; o < CH; ++o) Wt[i * CH + o] = W[o * CH + i] * scale;
}

__global__ void k_deg(const int* __restrict__ eidx, const int* __restrict__ flag,
                      int* __restrict__ deg) {
    int e = blockIdx.x * blockDim.x + threadIdx.x;
    if (e >= N_EDGES) return;
    int st = *flag;
    int col = eidx[(size_t)st * (size_t)(N_EDGES + e)];
    atomicAdd(&deg[col], 1);
}

// single block: exclusive prefix sum deg -> rowptr, cursor=rowptr, dinv=rsqrt(deg+1)
#define SCAN_T 1024
__global__ __launch_bounds__(SCAN_T) void k_scan(const int* __restrict__ deg,
                                                 int* __restrict__ rowptr,
                                                 int* __restrict__ cursor,
                                                 float* __restrict__ dinv) {
    __shared__ int part[SCAN_T];
    int t = threadIdx.x;
    const int CHUNK = (N_NODES + SCAN_T - 1) / SCAN_T;  // 49
    int lo = t * CHUNK, hi = min(lo + CHUNK, N_NODES);
    int s = 0;
    for (int i = lo; i < hi; ++i) s += deg[i];
    part[t] = s;
    __syncthreads();
    for (int off = 1; off < SCAN_T; off <<= 1) {
        int v = (t >= off) ? part[t - off] : 0;
        __syncthreads();
        part[t] += v;
        __syncthreads();
    }
    int base = (t > 0) ? part[t - 1] : 0;
    for (int i = lo; i < hi; ++i) {
        int d = deg[i];
        rowptr[i] = base;
        cursor[i] = base;
        dinv[i] = rsqrtf((float)(d + 1));
        base += d;
    }
    if (t == SCAN_T - 1) rowptr[N_NODES] = base;
}

__global__ void k_fill(const int* __restrict__ eidx, const int* __restrict__ flag,
                       int* __restrict__ cursor, int* __restrict__ src) {
    int e = blockIdx.x * blockDim.x + threadIdx.x;
    if (e >= N_EDGES) return;
    int st = *flag;
    int row = eidx[(size_t)st * (size_t)e];
    int col = eidx[(size_t)st * (size_t)(N_EDGES + e)];
    int pos = atomicAdd(&cursor[col], 1);
    src[pos] = row;
}

// hs = (x @ Wn^T) * dinv[row].  Block: 256 threads, 32 rows x 128 cols.
__global__ __launch_bounds__(256) void k_gemm(const float* __restrict__ x,
                                              const float* __restrict__ Wt,
                                              const float* __restrict__ dinv,
                                              float* __restrict__ hs) {
    __shared__ float xs[32 * 128];  // 16 KB
    int t = threadIdx.x;
    int base = blockIdx.x * 32;
    #pragma unroll
    for (int j = 0; j < 4; ++j) {
        int f4 = j * 256 + t;
        int r = f4 >> 5;
        int c = (f4 & 31) * 4;
        int n = base + r;
        float4 v = make_float4(0.f, 0.f, 0.f, 0.f);
        if (n < N_NODES) v = *(const float4*)&x[(size_t)n * CH + c];
        *(float4*)&xs[r * 128 + c] = v;
    }
    __syncthreads();
    int tx = t & 31;
    int ty = t >> 5;
    float acc[4][4] = {};
    const float* wp = Wt + 4 * tx;
    #pragma unroll 2
    for (int k = 0; k < CH; ++k) {
        float4 bv = *(const float4*)&wp[k * CH];
        #pragma unroll
        for (int r = 0; r < 4; ++r) {
            float a = xs[(4 * ty + r) * 128 + k];
            acc[r][0] += a * bv.x;
            acc[r][1] += a * bv.y;
            acc[r][2] += a * bv.z;
            acc[r][3] += a * bv.w;
        }
    }
    #pragma unroll
    for (int r = 0; r < 4; ++r) {
        int n = base + 4 * ty + r;
        if (n < N_NODES) {
            float di = dinv[n];
            float4 v = make_float4(acc[r][0] * di, acc[r][1] * di,
                                   acc[r][2] * di, acc[r][3] * di);
            *(float4*)&hs[(size_t)n * CH + 4 * tx] = v;
        }
    }
}

// one wave per destination node; lane handles 2 channels (float2)
// out[n] = (sum_{r in in-edges} hs[r] + hs[n]) * dinv[n] + b
__global__ __launch_bounds__(256) void k_gather(const int* __restrict__ rowptr,
                                                const int* __restrict__ src,
                                                const float* __restrict__ hs,
                                                const float* __restrict__ dinv,
                                                const float* __restrict__ b,
                                                float* __restrict__ out) {
    int wid = threadIdx.x >> 6;
    int lane = threadIdx.x & 63;
    int n = blockIdx.x * 4 + wid;
    if (n >= N_NODES) return;
    int j = rowptr[n];
    int jend = rowptr[n + 1];
    int c = lane * 2;
    float2 acc = make_float2(0.f, 0.f);
    for (; j + 4 <= jend; j += 4) {
        int r0 = src[j], r1 = src[j + 1], r2 = src[j + 2], r3 = src[j + 3];
        float2 v0 = *(const float2*)&hs[(size_t)r0 * CH + c];
        float2 v1 = *(const float2*)&hs[(size_t)r1 * CH + c];
        float2 v2 = *(const float2*)&hs[(size_t)r2 * CH + c];
        float2 v3 = *(const float2*)&hs[(size_t)r3 * CH + c];
        acc.x += (v0.x + v1.x) + (v2.x + v3.x);
        acc.y += (v0.y + v1.y) + (v2.y + v3.y);
    }
    for (; j < jend; ++j) {
        int r = src[j];
        float2 v = *(const float2*)&hs[(size_t)r * CH + c];
        acc.x += v.x;
        acc.y += v.y;
    }
    float di = dinv[n];
    float2 sv = *(const float2*)&hs[(size_t)n * CH + c];
    float2 bv = *(const float2*)&b[c];
    float2 o;
    o.x = (acc.x + sv.x) * di + bv.x;
    o.y = (acc.y + sv.y) * di + bv.y;
    *(float2*)&out[(size_t)n * CH + c] = o;
}

extern "C" void kernel_launch(void* const* d_in, const int* in_sizes, int n_in,
                              void* d_out, int out_size, void* d_ws, size_t ws_size,
                              hipStream_t stream) {
    const float* x = (const float*)d_in[0];
    const int* eidx = (const int*)d_in[1];
    const float* W = (const float*)d_in[2];
    const float* b = (const float*)d_in[3];
    float* out = (float*)d_out;

    char* ws = (char*)d_ws;
    float* Wt     = (float*)(ws + WS_WT);
    int*   flag   = (int*)(ws + WS_FLAG);
    int*   deg    = (int*)(ws + WS_DEG);
    int*   rowptr = (int*)(ws + WS_ROWPTR);
    int*   cursor = (int*)(ws + WS_CURSOR);
    float* dinv   = (float*)(ws + WS_DINV);
    int*   srcarr = (int*)(ws + WS_SRC);
    float* hs     = (float*)(ws + WS_H);

    hipMemsetAsync(deg, 0, N_NODES * sizeof(int), stream);
    k_prep<<<1, 128, 0, stream>>>(W, eidx, Wt, flag);
    k_deg<<<(N_EDGES + 255) / 256, 256, 0, stream>>>(eidx, flag, deg);
    k_scan<<<1, SCAN_T, 0, stream>>>(deg, rowptr, cursor, dinv);
    k_fill<<<(N_EDGES + 255) / 256, 256, 0, stream>>>(eidx, flag, cursor, srcarr);
    k_gemm<<<(N_NODES + 31) / 32, 256, 0, stream>>>(x, Wt, dinv, hs);
    k_gather<<<(N_NODES + 3) / 4, 256, 0, stream>>>(rowptr, srcarr, hs, dinv, b, out);
}

// Round 3
// 358.397 us; speedup vs baseline: 3.9969x; 1.3361x over previous
//
#include <hip/hip_runtime.h>

#define N_NODES 50000
#define N_EDGES 1600000
#define CH 128
#define NBLK 196  // ceil(N_NODES/256)

// ws layout (bytes), total ~33 MB:
#define WS_WT      0         // Wt [128*128] f32 (renormed, transposed)
#define WS_FLAG    65536     // int: edge_index elem stride (1=int32, 2=int64 low word)
#define WS_DEG     131072    // deg [N] int
#define WS_ROWPTR  393216    // rowptr [N+1] int
#define WS_CURSOR  655360    // cursor [N] int
#define WS_DINV    917504    // dinv [N] f32
#define WS_BSUM    1130496   // bsum/boff [NBLK] int
#define WS_SRC     1179648   // src [E] int
#define WS_H       7684096   // hs [N*128] f32 (h pre-scaled by dinv[row])

__global__ void k_prep(const float* __restrict__ W, const int* __restrict__ eidx,
                       float* __restrict__ Wt, int* __restrict__ flag) {
    int i = threadIdx.x;  // 128 threads
    if (i < 64) {
        int v = eidx[2 * i + 1];
        unsigned long long m = __ballot(v == 0);
        if (i == 0) *flag = (m == ~0ull) ? 2 : 1;
    }
    float s = 0.f;
    for (int o = 0; o < CH; ++o) { float w = W[o * CH + i]; s += w * w; }
    float scale = (s > 1.0f) ? rsqrtf(s) : 1.0f;
    for (int o = 0; o < CH; ++o) Wt[i * CH + o] = W[o * CH + i] * scale;
}

__global__ void k_deg(const int* __restrict__ eidx, const int* __restrict__ flag,
                      int* __restrict__ deg) {
    int e = blockIdx.x * blockDim.x + threadIdx.x;
    if (e >= N_EDGES) return;
    int st = *flag;
    int col = eidx[(size_t)st * (size_t)(N_EDGES + e)];
    atomicAdd(&deg[col], 1);
}

// level 1: per-block sum of deg
__global__ __launch_bounds__(256) void k_scan1(const int* __restrict__ deg,
                                               int* __restrict__ bsum) {
    __shared__ int sh[256];
    int t = threadIdx.x;
    int i = blockIdx.x * 256 + t;
    int v = (i < N_NODES) ? deg[i] : 0;
    sh[t] = v;
    __syncthreads();
    for (int off = 128; off > 0; off >>= 1) {
        if (t < off) sh[t] += sh[t + off];
        __syncthreads();
    }
    if (t == 0) bsum[blockIdx.x] = sh[0];
}

// level 2: exclusive scan of NBLK partials (single small block)
__global__ __launch_bounds__(256) void k_scan2(int* __restrict__ bsum,
                                               int* __restrict__ rowptr) {
    __shared__ int sh[256];
    int t = threadIdx.x;
    int v = (t < NBLK) ? bsum[t] : 0;
    sh[t] = v;
    __syncthreads();
    for (int off = 1; off < 256; off <<= 1) {
        int u = (t >= off) ? sh[t - off] : 0;
        __syncthreads();
        sh[t] += u;
        __syncthreads();
    }
    int excl = sh[t] - v;
    if (t < NBLK) bsum[t] = excl;
    if (t == NBLK - 1) rowptr[N_NODES] = excl + v;  // total (= N_EDGES)
}

// level 3: per-block exclusive scan + block offset; fused rowptr/cursor/dinv
__global__ __launch_bounds__(256) void k_scan3(const int* __restrict__ deg,
                                               const int* __restrict__ boff,
                                               int* __restrict__ rowptr,
                                               int* __restrict__ cursor,
                                               float* __restrict__ dinv) {
    __shared__ int sh[256];
    int t = threadIdx.x;
    int i = blockIdx.x * 256 + t;
    int v = (i < N_NODES) ? deg[i] : 0;
    sh[t] = v;
    __syncthreads();
    for (int off = 1; off < 256; off <<= 1) {
        int u = (t >= off) ? sh[t - off] : 0;
        __syncthreads();
        sh[t] += u;
        __syncthreads();
    }
    if (i < N_NODES) {
        int g = boff[blockIdx.x] + sh[t] - v;
        rowptr[i] = g;
        cursor[i] = g;
        dinv[i] = rsqrtf((float)(v + 1));
    }
}

__global__ void k_fill(const int* __restrict__ eidx, const int* __restrict__ flag,
                       int* __restrict__ cursor, int* __restrict__ src) {
    int e = blockIdx.x * blockDim.x + threadIdx.x;
    if (e >= N_EDGES) return;
    int st = *flag;
    int row = eidx[(size_t)st * (size_t)e];
    int col = eidx[(size_t)st * (size_t)(N_EDGES + e)];
    int pos = atomicAdd(&cursor[col], 1);
    src[pos] = row;
}

// hs = (x @ Wn^T) * dinv[row].  Block: 256 threads, 32 rows x 128 cols.
__global__ __launch_bounds__(256) void k_gemm(const float* __restrict__ x,
                                              const float* __restrict__ Wt,
                                              const float* __restrict__ dinv,
                                              float* __restrict__ hs) {
    __shared__ float xs[32 * 128];  // 16 KB
    int t = threadIdx.x;
    int base = blockIdx.x * 32;
    #pragma unroll
    for (int j = 0; j < 4; ++j) {
        int f4 = j * 256 + t;
        int r = f4 >> 5;
        int c = (f4 & 31) * 4;
        int n = base + r;
        float4 v = make_float4(0.f, 0.f, 0.f, 0.f);
        if (n < N_NODES) v = *(const float4*)&x[(size_t)n * CH + c];
        *(float4*)&xs[r * 128 + c] = v;
    }
    __syncthreads();
    int tx = t & 31;
    int ty = t >> 5;
    float acc[4][4] = {};
    const float* wp = Wt + 4 * tx;
    #pragma unroll 2
    for (int k = 0; k < CH; ++k) {
        float4 bv = *(const float4*)&wp[k * CH];
        #pragma unroll
        for (int r = 0; r < 4; ++r) {
            float a = xs[(4 * ty + r) * 128 + k];
            acc[r][0] += a * bv.x;
            acc[r][1] += a * bv.y;
            acc[r][2] += a * bv.z;
            acc[r][3] += a * bv.w;
        }
    }
    #pragma unroll
    for (int r = 0; r < 4; ++r) {
        int n = base + 4 * ty + r;
        if (n < N_NODES) {
            float di = dinv[n];
            float4 v = make_float4(acc[r][0] * di, acc[r][1] * di,
                                   acc[r][2] * di, acc[r][3] * di);
            *(float4*)&hs[(size_t)n * CH + 4 * tx] = v;
        }
    }
}

// one wave per destination node; lane handles 2 channels (float2)
__global__ __launch_bounds__(256) void k_gather(const int* __restrict__ rowptr,
                                                const int* __restrict__ src,
                                                const float* __restrict__ hs,
                                                const float* __restrict__ dinv,
                                                const float* __restrict__ b,
                                                float* __restrict__ out) {
    int wid = threadIdx.x >> 6;
    int lane = threadIdx.x & 63;
    int n = blockIdx.x * 4 + wid;
    if (n >= N_NODES) return;
    int j = rowptr[n];
    int jend = rowptr[n + 1];
    int c = lane * 2;
    float2 acc = make_float2(0.f, 0.f);
    for (; j + 4 <= jend; j += 4) {
        int r0 = src[j], r1 = src[j + 1], r2 = src[j + 2], r3 = src[j + 3];
        float2 v0 = *(const float2*)&hs[(size_t)r0 * CH + c];
        float2 v1 = *(const float2*)&hs[(size_t)r1 * CH + c];
        float2 v2 = *(const float2*)&hs[(size_t)r2 * CH + c];
        float2 v3 = *(const float2*)&hs[(size_t)r3 * CH + c];
        acc.x += (v0.x + v1.x) + (v2.x + v3.x);
        acc.y += (v0.y + v1.y) + (v2.y + v3.y);
    }
    for (; j < jend; ++j) {
        int r = src[j];
        float2 v = *(const float2*)&hs[(size_t)r * CH + c];
        acc.x += v.x;
        acc.y += v.y;
    }
    float di = dinv[n];
    float2 sv = *(const float2*)&hs[(size_t)n * CH + c];
    float2 bv = *(const float2*)&b[c];
    float2 o;
    o.x = (acc.x + sv.x) * di + bv.x;
    o.y = (acc.y + sv.y) * di + bv.y;
    *(float2*)&out[(size_t)n * CH + c] = o;
}

extern "C" void kernel_launch(void* const* d_in, const int* in_sizes, int n_in,
                              void* d_out, int out_size, void* d_ws, size_t ws_size,
                              hipStream_t stream) {
    const float* x = (const float*)d_in[0];
    const int* eidx = (const int*)d_in[1];
    const float* W = (const float*)d_in[2];
    const float* b = (const float*)d_in[3];
    float* out = (float*)d_out;

    char* ws = (char*)d_ws;
    float* Wt     = (float*)(ws + WS_WT);
    int*   flag   = (int*)(ws + WS_FLAG);
    int*   deg    = (int*)(ws + WS_DEG);
    int*   rowptr = (int*)(ws + WS_ROWPTR);
    int*   cursor = (int*)(ws + WS_CURSOR);
    float* dinv   = (float*)(ws + WS_DINV);
    int*   bsum   = (int*)(ws + WS_BSUM);
    int*   srcarr = (int*)(ws + WS_SRC);
    float* hs     = (float*)(ws + WS_H);

    hipMemsetAsync(deg, 0, N_NODES * sizeof(int), stream);
    k_prep<<<1, 128, 0, stream>>>(W, eidx, Wt, flag);
    k_deg<<<(N_EDGES + 255) / 256, 256, 0, stream>>>(eidx, flag, deg);
    k_scan1<<<NBLK, 256, 0, stream>>>(deg, bsum);
    k_scan2<<<1, 256, 0, stream>>>(bsum, rowptr);
    k_scan3<<<NBLK, 256, 0, stream>>>(deg, bsum, rowptr, cursor, dinv);
    k_fill<<<(N_EDGES + 255) / 256, 256, 0, stream>>>(eidx, flag, cursor, srcarr);
    k_gemm<<<(N_NODES + 31) / 32, 256, 0, stream>>>(x, Wt, dinv, hs);
    k_gather<<<(N_NODES + 3) / 4, 256, 0, stream>>>(rowptr, srcarr, hs, dinv, b, out);
}

// Round 4
// 246.064 us; speedup vs baseline: 5.8216x; 1.4565x over previous
//
#include <hip/hip_runtime.h>

#define N_NODES 50000
#define N_EDGES 1600000
#define CH 128
#define NB 196        // buckets of 256 nodes: bucket = col >> 8
#define CHUNK_E 8192
#define NCHUNK 196    // ceil(N_EDGES / CHUNK_E)

// ws layout (bytes), total ~33 MB (ebuf aliases the hs region — dead before gemm):
#define WS_WT      0         // Wt [128*128] f32
#define WS_FLAG    65536     // int: edge elem stride (1=int32, 2=int64 low word)
#define WS_CNT     65600     // cnt [NCHUNK*NB] int (~154KB)
#define WS_OFFS    219264    // offs [NCHUNK*NB] int (~154KB)
#define WS_BSTART  372928    // bstart [NB+1] int
#define WS_ROWPTR  373760    // rowptr [N+1] int
#define WS_DINV    573768    // dinv [N] f32  (+ padding to 8B align below)
#define WS_SRC     773768    // src [E] int (6.4MB)
#define WS_H       7173768   // hs [N*128] f32 (25.6MB); ebuf [E] u32 aliases its head

__global__ void k_prep(const float* __restrict__ W, const int* __restrict__ eidx,
                       float* __restrict__ Wt, int* __restrict__ flag) {
    int i = threadIdx.x;  // 128 threads
    if (i < 64) {
        int v = eidx[2 * i + 1];
        unsigned long long m = __ballot(v == 0);
        if (i == 0) *flag = (m == ~0ull) ? 2 : 1;
    }
    float s = 0.f;
    for (int o = 0; o < CH; ++o) { float w = W[o * CH + i]; s += w * w; }
    float scale = (s > 1.0f) ? rsqrtf(s) : 1.0f;
    for (int o = 0; o < CH; ++o) Wt[i * CH + o] = W[o * CH + i] * scale;
}

// per-chunk bucket histogram (LDS, no global atomics)
__global__ __launch_bounds__(256) void k_part1(const int* __restrict__ eidx,
                                               const int* __restrict__ flag,
                                               int* __restrict__ cnt) {
    __shared__ int lc[256];
    int t = threadIdx.x, c = blockIdx.x;
    int st = *flag;
    lc[t] = 0;
    __syncthreads();
    long base = (long)c * CHUNK_E;
    #pragma unroll
    for (int i = 0; i < CHUNK_E / 256; ++i) {
        long e = base + i * 256 + t;
        if (e < N_EDGES) {
            int col = eidx[(size_t)st * (size_t)(N_EDGES + e)];
            atomicAdd(&lc[col >> 8], 1);
        }
    }
    __syncthreads();
    if (t < NB) cnt[c * NB + t] = lc[t];
}

// scan cnt -> absolute offsets per (chunk,bucket) + bstart
__global__ __launch_bounds__(256) void k_coff(const int* __restrict__ cnt,
                                              int* __restrict__ offs,
                                              int* __restrict__ bstart) {
    __shared__ int sh[256];
    int t = threadIdx.x;
    int run = 0;
    if (t < NB) {
        #pragma unroll 4
        for (int c = 0; c < NCHUNK; ++c) run += cnt[c * NB + t];
    }
    sh[t] = run;
    __syncthreads();
    for (int off = 1; off < 256; off <<= 1) {
        int u = (t >= off) ? sh[t - off] : 0;
        __syncthreads();
        sh[t] += u;
        __syncthreads();
    }
    int excl = sh[t] - run;
    if (t < NB) {
        bstart[t] = excl;
        if (t == NB - 1) bstart[NB] = excl + run;
        int base = excl;
        #pragma unroll 4
        for (int c = 0; c < NCHUNK; ++c) {
            offs[c * NB + t] = base;
            base += cnt[c * NB + t];
        }
    }
}

// scatter edges into bucket-partitioned ebuf (packed row:16 | colLow:8 << 16)
__global__ __launch_bounds__(256) void k_part2(const int* __restrict__ eidx,
                                               const int* __restrict__ flag,
                                               const int* __restrict__ offs,
                                               unsigned int* __restrict__ ebuf) {
    __shared__ int lcur[256];
    int t = threadIdx.x, c = blockIdx.x;
    int st = *flag;
    if (t < NB) lcur[t] = offs[c * NB + t];
    __syncthreads();
    long base = (long)c * CHUNK_E;
    #pragma unroll
    for (int i = 0; i < CHUNK_E / 256; ++i) {
        long e = base + i * 256 + t;
        if (e < N_EDGES) {
            int row = eidx[(size_t)st * (size_t)e];
            int col = eidx[(size_t)st * (size_t)(N_EDGES + e)];
            int pos = atomicAdd(&lcur[col >> 8], 1);
            ebuf[pos] = (unsigned int)(row & 0xFFFF) | ((unsigned int)(col & 255) << 16);
        }
    }
}

// per-bucket: histogram -> deg/rowptr/dinv (fused), then exact scatter ebuf -> src
__global__ __launch_bounds__(256) void k_sort(const unsigned int* __restrict__ ebuf,
                                              const int* __restrict__ bstart,
                                              int* __restrict__ rowptr,
                                              float* __restrict__ dinv,
                                              int* __restrict__ src) {
    __shared__ int ldeg[256];
    __shared__ int lcur[256];
    int t = threadIdx.x, b = blockIdx.x;
    int i0 = bstart[b], i1 = bstart[b + 1];
    ldeg[t] = 0;
    __syncthreads();
    for (int i = i0 + t; i < i1; i += 256) {
        unsigned int p = ebuf[i];
        atomicAdd(&ldeg[(p >> 16) & 255], 1);
    }
    __syncthreads();
    int d = ldeg[t];
    // exclusive scan of ldeg
    __shared__ int sh[256];
    sh[t] = d;
    __syncthreads();
    for (int off = 1; off < 256; off <<= 1) {
        int u = (t >= off) ? sh[t - off] : 0;
        __syncthreads();
        sh[t] += u;
        __syncthreads();
    }
    int local_rp = i0 + sh[t] - d;
    int n = (b << 8) + t;
    if (n < N_NODES) {
        rowptr[n] = local_rp;
        dinv[n] = rsqrtf((float)(d + 1));
    }
    if (b == NB - 1 && t == 0) rowptr[N_NODES] = N_EDGES;
    lcur[t] = local_rp;
    __syncthreads();
    for (int i = i0 + t; i < i1; i += 256) {
        unsigned int p = ebuf[i];
        int pos = atomicAdd(&lcur[(p >> 16) & 255], 1);
        src[pos] = (int)(p & 0xFFFF);
    }
}

// hs = (x @ Wn^T) * dinv[row].  Block: 256 threads, 32 rows x 128 cols.
__global__ __launch_bounds__(256) void k_gemm(const float* __restrict__ x,
                                              const float* __restrict__ Wt,
                                              const float* __restrict__ dinv,
                                              float* __restrict__ hs) {
    __shared__ float xs[32 * 128];  // 16 KB
    int t = threadIdx.x;
    int base = blockIdx.x * 32;
    #pragma unroll
    for (int j = 0; j < 4; ++j) {
        int f4 = j * 256 + t;
        int r = f4 >> 5;
        int c = (f4 & 31) * 4;
        int n = base + r;
        float4 v = make_float4(0.f, 0.f, 0.f, 0.f);
        if (n < N_NODES) v = *(const float4*)&x[(size_t)n * CH + c];
        *(float4*)&xs[r * 128 + c] = v;
    }
    __syncthreads();
    int tx = t & 31;
    int ty = t >> 5;
    float acc[4][4] = {};
    const float* wp = Wt + 4 * tx;
    #pragma unroll 2
    for (int k = 0; k < CH; ++k) {
        float4 bv = *(const float4*)&wp[k * CH];
        #pragma unroll
        for (int r = 0; r < 4; ++r) {
            float a = xs[(4 * ty + r) * 128 + k];
            acc[r][0] += a * bv.x;
            acc[r][1] += a * bv.y;
            acc[r][2] += a * bv.z;
            acc[r][3] += a * bv.w;
        }
    }
    #pragma unroll
    for (int r = 0; r < 4; ++r) {
        int n = base + 4 * ty + r;
        if (n < N_NODES) {
            float di = dinv[n];
            float4 v = make_float4(acc[r][0] * di, acc[r][1] * di,
                                   acc[r][2] * di, acc[r][3] * di);
            *(float4*)&hs[(size_t)n * CH + 4 * tx] = v;
        }
    }
}

// one wave per destination node; lane handles 2 channels (float2)
__global__ __launch_bounds__(256) void k_gather(const int* __restrict__ rowptr,
                                                const int* __restrict__ src,
                                                const float* __restrict__ hs,
                                                const float* __restrict__ dinv,
                                                const float* __restrict__ b,
                                                float* __restrict__ out) {
    int wid = threadIdx.x >> 6;
    int lane = threadIdx.x & 63;
    int n = blockIdx.x * 4 + wid;
    if (n >= N_NODES) return;
    int j = rowptr[n];
    int jend = rowptr[n + 1];
    int c = lane * 2;
    float2 acc = make_float2(0.f, 0.f);
    for (; j + 4 <= jend; j += 4) {
        int r0 = src[j], r1 = src[j + 1], r2 = src[j + 2], r3 = src[j + 3];
        float2 v0 = *(const float2*)&hs[(size_t)r0 * CH + c];
        float2 v1 = *(const float2*)&hs[(size_t)r1 * CH + c];
        float2 v2 = *(const float2*)&hs[(size_t)r2 * CH + c];
        float2 v3 = *(const float2*)&hs[(size_t)r3 * CH + c];
        acc.x += (v0.x + v1.x) + (v2.x + v3.x);
        acc.y += (v0.y + v1.y) + (v2.y + v3.y);
    }
    for (; j < jend; ++j) {
        int r = src[j];
        float2 v = *(const float2*)&hs[(size_t)r * CH + c];
        acc.x += v.x;
        acc.y += v.y;
    }
    float di = dinv[n];
    float2 sv = *(const float2*)&hs[(size_t)n * CH + c];
    float2 bv = *(const float2*)&b[c];
    float2 o;
    o.x = (acc.x + sv.x) * di + bv.x;
    o.y = (acc.y + sv.y) * di + bv.y;
    *(float2*)&out[(size_t)n * CH + c] = o;
}

extern "C" void kernel_launch(void* const* d_in, const int* in_sizes, int n_in,
                              void* d_out, int out_size, void* d_ws, size_t ws_size,
                              hipStream_t stream) {
    const float* x = (const float*)d_in[0];
    const int* eidx = (const int*)d_in[1];
    const float* W = (const float*)d_in[2];
    const float* b = (const float*)d_in[3];
    float* out = (float*)d_out;

    char* ws = (char*)d_ws;
    float* Wt            = (float*)(ws + WS_WT);
    int*   flag          = (int*)(ws + WS_FLAG);
    int*   cnt           = (int*)(ws + WS_CNT);
    int*   offs          = (int*)(ws + WS_OFFS);
    int*   bstart        = (int*)(ws + WS_BSTART);
    int*   rowptr        = (int*)(ws + WS_ROWPTR);
    float* dinv          = (float*)(ws + WS_DINV);
    int*   srcarr        = (int*)(ws + WS_SRC);
    float* hs            = (float*)(ws + WS_H);
    unsigned int* ebuf   = (unsigned int*)(ws + WS_H);  // alias: dead before k_gemm

    k_prep<<<1, 128, 0, stream>>>(W, eidx, Wt, flag);
    k_part1<<<NCHUNK, 256, 0, stream>>>(eidx, flag, cnt);
    k_coff<<<1, 256, 0, stream>>>(cnt, offs, bstart);
    k_part2<<<NCHUNK, 256, 0, stream>>>(eidx, flag, offs, ebuf);
    k_sort<<<NB, 256, 0, stream>>>(ebuf, bstart, rowptr, dinv, srcarr);
    k_gemm<<<(N_NODES + 31) / 32, 256, 0, stream>>>(x, Wt, dinv, hs);
    k_gather<<<(N_NODES + 3) / 4, 256, 0, stream>>>(rowptr, srcarr, hs, dinv, b, out);
}

// Round 5
// 193.854 us; speedup vs baseline: 7.3895x; 1.2693x over previous
//
#include <hip/hip_runtime.h>

#define N_NODES 50000
#define N_EDGES 1600000
#define CH 128
#define NB 196        // buckets of 256 nodes: bucket = col >> 8
#define CHUNK_E 8192
#define NCHUNK 196    // ceil(N_EDGES / CHUNK_E)

// ws layout (bytes), total ~20 MB (ebuf aliases hs16 head — dead before k_gemm):
#define WS_WT      0         // Wt [128*128] f32
#define WS_FLAG    65536     // int: edge elem stride (1=int32, 2=int64 low word)
#define WS_CNT     65600     // cnt [NCHUNK*NB] int
#define WS_OFFS    219264    // offs [NCHUNK*NB] int
#define WS_BSTART  372928    // bstart [NB+1] int
#define WS_ROWPTR  373760    // rowptr [N+1] int
#define WS_DINV    573768    // dinv [N] f32
#define WS_SRC     773768    // src [E] int (6.4MB)
#define WS_H       7173768   // hs16 [N*128] bf16 (12.8MB); ebuf [E] u32 aliases head

__device__ __forceinline__ unsigned int pack_bf16(float a, float b) {
    unsigned int ua = __builtin_bit_cast(unsigned int, a);
    unsigned int ub = __builtin_bit_cast(unsigned int, b);
    ua = (ua + 0x7FFFu + ((ua >> 16) & 1u)) >> 16;   // RNE
    ub = (ub + 0x7FFFu + ((ub >> 16) & 1u)) >> 16;
    return ua | (ub << 16);
}

__device__ __forceinline__ float bf_lo(unsigned int v) {
    return __builtin_bit_cast(float, v << 16);
}
__device__ __forceinline__ float bf_hi(unsigned int v) {
    return __builtin_bit_cast(float, v & 0xFFFF0000u);
}

__global__ void k_prep(const float* __restrict__ W, const int* __restrict__ eidx,
                       float* __restrict__ Wt, int* __restrict__ flag) {
    int i = threadIdx.x;  // 128 threads
    if (i < 64) {
        int v = eidx[2 * i + 1];
        unsigned long long m = __ballot(v == 0);
        if (i == 0) *flag = (m == ~0ull) ? 2 : 1;
    }
    float s = 0.f;
    for (int o = 0; o < CH; ++o) { float w = W[o * CH + i]; s += w * w; }
    float scale = (s > 1.0f) ? rsqrtf(s) : 1.0f;
    for (int o = 0; o < CH; ++o) Wt[i * CH + o] = W[o * CH + i] * scale;
}

// per-chunk bucket histogram (LDS, no global atomics)
__global__ __launch_bounds__(256) void k_part1(const int* __restrict__ eidx,
                                               const int* __restrict__ flag,
                                               int* __restrict__ cnt) {
    __shared__ int lc[256];
    int t = threadIdx.x, c = blockIdx.x;
    int st = *flag;
    lc[t] = 0;
    __syncthreads();
    long base = (long)c * CHUNK_E;
    #pragma unroll
    for (int i = 0; i < CHUNK_E / 256; ++i) {
        long e = base + i * 256 + t;
        if (e < N_EDGES) {
            int col = eidx[(size_t)st * (size_t)(N_EDGES + e)];
            atomicAdd(&lc[col >> 8], 1);
        }
    }
    __syncthreads();
    if (t < NB) cnt[c * NB + t] = lc[t];
}

// scan cnt -> absolute offsets per (chunk,bucket) + bstart
__global__ __launch_bounds__(256) void k_coff(const int* __restrict__ cnt,
                                              int* __restrict__ offs,
                                              int* __restrict__ bstart) {
    __shared__ int sh[256];
    int t = threadIdx.x;
    int run = 0;
    if (t < NB) {
        #pragma unroll 4
        for (int c = 0; c < NCHUNK; ++c) run += cnt[c * NB + t];
    }
    sh[t] = run;
    __syncthreads();
    for (int off = 1; off < 256; off <<= 1) {
        int u = (t >= off) ? sh[t - off] : 0;
        __syncthreads();
        sh[t] += u;
        __syncthreads();
    }
    int excl = sh[t] - run;
    if (t < NB) {
        bstart[t] = excl;
        if (t == NB - 1) bstart[NB] = excl + run;
        int base = excl;
        #pragma unroll 4
        for (int c = 0; c < NCHUNK; ++c) {
            offs[c * NB + t] = base;
            base += cnt[c * NB + t];
        }
    }
}

// scatter edges into bucket-partitioned ebuf (packed row:16 | colLow:8 << 16)
__global__ __launch_bounds__(256) void k_part2(const int* __restrict__ eidx,
                                               const int* __restrict__ flag,
                                               const int* __restrict__ offs,
                                               unsigned int* __restrict__ ebuf) {
    __shared__ int lcur[256];
    int t = threadIdx.x, c = blockIdx.x;
    int st = *flag;
    if (t < NB) lcur[t] = offs[c * NB + t];
    __syncthreads();
    long base = (long)c * CHUNK_E;
    #pragma unroll
    for (int i = 0; i < CHUNK_E / 256; ++i) {
        long e = base + i * 256 + t;
        if (e < N_EDGES) {
            int row = eidx[(size_t)st * (size_t)e];
            int col = eidx[(size_t)st * (size_t)(N_EDGES + e)];
            int pos = atomicAdd(&lcur[col >> 8], 1);
            ebuf[pos] = (unsigned int)(row & 0xFFFF) | ((unsigned int)(col & 255) << 16);
        }
    }
}

// per-bucket: histogram -> rowptr/dinv (fused), then exact scatter ebuf -> src
__global__ __launch_bounds__(256) void k_sort(const unsigned int* __restrict__ ebuf,
                                              const int* __restrict__ bstart,
                                              int* __restrict__ rowptr,
                                              float* __restrict__ dinv,
                                              int* __restrict__ src) {
    __shared__ int ldeg[256];
    __shared__ int lcur[256];
    __shared__ int sh[256];
    int t = threadIdx.x, b = blockIdx.x;
    int i0 = bstart[b], i1 = bstart[b + 1];
    ldeg[t] = 0;
    __syncthreads();
    for (int i = i0 + t; i < i1; i += 256) {
        unsigned int p = ebuf[i];
        atomicAdd(&ldeg[(p >> 16) & 255], 1);
    }
    __syncthreads();
    int d = ldeg[t];
    sh[t] = d;
    __syncthreads();
    for (int off = 1; off < 256; off <<= 1) {
        int u = (t >= off) ? sh[t - off] : 0;
        __syncthreads();
        sh[t] += u;
        __syncthreads();
    }
    int local_rp = i0 + sh[t] - d;
    int n = (b << 8) + t;
    if (n < N_NODES) {
        rowptr[n] = local_rp;
        dinv[n] = rsqrtf((float)(d + 1));
    }
    if (b == NB - 1 && t == 0) rowptr[N_NODES] = N_EDGES;
    lcur[t] = local_rp;
    __syncthreads();
    for (int i = i0 + t; i < i1; i += 256) {
        unsigned int p = ebuf[i];
        int pos = atomicAdd(&lcur[(p >> 16) & 255], 1);
        src[pos] = (int)(p & 0xFFFF);
    }
}

// hs16 = bf16((x @ Wn^T) * dinv[row]).  Block: 256 threads, 32 rows x 128 cols.
__global__ __launch_bounds__(256) void k_gemm(const float* __restrict__ x,
                                              const float* __restrict__ Wt,
                                              const float* __restrict__ dinv,
                                              unsigned int* __restrict__ hs16) {
    __shared__ float xs[32 * 128];  // 16 KB
    int t = threadIdx.x;
    int base = blockIdx.x * 32;
    #pragma unroll
    for (int j = 0; j < 4; ++j) {
        int f4 = j * 256 + t;
        int r = f4 >> 5;
        int c = (f4 & 31) * 4;
        int n = base + r;
        float4 v = make_float4(0.f, 0.f, 0.f, 0.f);
        if (n < N_NODES) v = *(const float4*)&x[(size_t)n * CH + c];
        *(float4*)&xs[r * 128 + c] = v;
    }
    __syncthreads();
    int tx = t & 31;
    int ty = t >> 5;
    float acc[4][4] = {};
    const float* wp = Wt + 4 * tx;
    #pragma unroll 2
    for (int k = 0; k < CH; ++k) {
        float4 bv = *(const float4*)&wp[k * CH];
        #pragma unroll
        for (int r = 0; r < 4; ++r) {
            float a = xs[(4 * ty + r) * 128 + k];
            acc[r][0] += a * bv.x;
            acc[r][1] += a * bv.y;
            acc[r][2] += a * bv.z;
            acc[r][3] += a * bv.w;
        }
    }
    #pragma unroll
    for (int r = 0; r < 4; ++r) {
        int n = base + 4 * ty + r;
        if (n < N_NODES) {
            float di = dinv[n];
            uint2 v;
            v.x = pack_bf16(acc[r][0] * di, acc[r][1] * di);
            v.y = pack_bf16(acc[r][2] * di, acc[r][3] * di);
            *(uint2*)&hs16[(size_t)n * 64 + 2 * tx] = v;
        }
    }
}

// one wave per destination node; lane handles 2 channels (1 uint = 2 bf16)
__global__ __launch_bounds__(256) void k_gather(const int* __restrict__ rowptr,
                                                const int* __restrict__ src,
                                                const unsigned int* __restrict__ hs16,
                                                const float* __restrict__ dinv,
                                                const float* __restrict__ b,
                                                float* __restrict__ out) {
    int wid = threadIdx.x >> 6;
    int lane = threadIdx.x & 63;
    int n = blockIdx.x * 4 + wid;
    if (n >= N_NODES) return;
    int j = rowptr[n];
    int jend = rowptr[n + 1];
    float2 acc = make_float2(0.f, 0.f);
    for (; j + 4 <= jend; j += 4) {
        int r0 = src[j], r1 = src[j + 1], r2 = src[j + 2], r3 = src[j + 3];
        unsigned int v0 = hs16[(size_t)r0 * 64 + lane];
        unsigned int v1 = hs16[(size_t)r1 * 64 + lane];
        unsigned int v2 = hs16[(size_t)r2 * 64 + lane];
        unsigned int v3 = hs16[(size_t)r3 * 64 + lane];
        acc.x += (bf_lo(v0) + bf_lo(v1)) + (bf_lo(v2) + bf_lo(v3));
        acc.y += (bf_hi(v0) + bf_hi(v1)) + (bf_hi(v2) + bf_hi(v3));
    }
    for (; j < jend; ++j) {
        int r = src[j];
        unsigned int v = hs16[(size_t)r * 64 + lane];
        acc.x += bf_lo(v);
        acc.y += bf_hi(v);
    }
    float di = dinv[n];
    unsigned int sv = hs16[(size_t)n * 64 + lane];
    float2 bv = *(const float2*)&b[lane * 2];
    float2 o;
    o.x = (acc.x + bf_lo(sv)) * di + bv.x;
    o.y = (acc.y + bf_hi(sv)) * di + bv.y;
    *(float2*)&out[(size_t)n * CH + lane * 2] = o;
}

extern "C" void kernel_launch(void* const* d_in, const int* in_sizes, int n_in,
                              void* d_out, int out_size, void* d_ws, size_t ws_size,
                              hipStream_t stream) {
    const float* x = (const float*)d_in[0];
    const int* eidx = (const int*)d_in[1];
    const float* W = (const float*)d_in[2];
    const float* b = (const float*)d_in[3];
    float* out = (float*)d_out;

    char* ws = (char*)d_ws;
    float* Wt            = (float*)(ws + WS_WT);
    int*   flag          = (int*)(ws + WS_FLAG);
    int*   cnt           = (int*)(ws + WS_CNT);
    int*   offs          = (int*)(ws + WS_OFFS);
    int*   bstart        = (int*)(ws + WS_BSTART);
    int*   rowptr        = (int*)(ws + WS_ROWPTR);
    float* dinv          = (float*)(ws + WS_DINV);
    int*   srcarr        = (int*)(ws + WS_SRC);
    unsigned int* hs16   = (unsigned int*)(ws + WS_H);
    unsigned int* ebuf   = (unsigned int*)(ws + WS_H);  // alias: dead before k_gemm

    k_prep<<<1, 128, 0, stream>>>(W, eidx, Wt, flag);
    k_part1<<<NCHUNK, 256, 0, stream>>>(eidx, flag, cnt);
    k_coff<<<1, 256, 0, stream>>>(cnt, offs, bstart);
    k_part2<<<NCHUNK, 256, 0, stream>>>(eidx, flag, offs, ebuf);
    k_sort<<<NB, 256, 0, stream>>>(ebuf, bstart, rowptr, dinv, srcarr);
    k_gemm<<<(N_NODES + 31) / 32, 256, 0, stream>>>(x, Wt, dinv, hs16);
    k_gather<<<(N_NODES + 3) / 4, 256, 0, stream>>>(rowptr, srcarr, hs16, dinv, b, out);
}

// Round 6
// 168.239 us; speedup vs baseline: 8.5146x; 1.1523x over previous
//
#include <hip/hip_runtime.h>

#define N_NODES 50000
#define N_EDGES 1600000
#define CH 128
#define NB 196        // buckets of 256 nodes: bucket = col >> 8
#define CHUNK_E 8192
#define NCHUNK 196    // ceil(N_EDGES / CHUNK_E)

// ws layout (bytes), total ~20 MB (ebuf aliases hs16 head — dead before k_gemm):
#define WS_WBF     0         // Wbf [128 o][64 words] bf16-pairs (renormed W, 32KB)
#define WS_FLAG    65536     // int: edge elem stride (1=int32, 2=int64 low word)
#define WS_CNT     65600     // cnt [NCHUNK*NB] int
#define WS_OFFS    219264    // offs [NCHUNK*NB] int
#define WS_BSTART  372928    // bstart [NB+1] int
#define WS_ROWPTR  373760    // rowptr [N+1] int
#define WS_DINV    573768    // dinv [N] f32
#define WS_SRC     773768    // src [E] int (6.4MB)
#define WS_H       7173768   // hs16 [N*64] u32 (bf16 pairs, 12.8MB); ebuf aliases head

typedef __bf16 bf16x8 __attribute__((ext_vector_type(8)));
typedef float f32x4 __attribute__((ext_vector_type(4)));

__device__ __forceinline__ unsigned int pack_bf16(float a, float b) {
    unsigned int ua = __builtin_bit_cast(unsigned int, a);
    unsigned int ub = __builtin_bit_cast(unsigned int, b);
    ua = (ua + 0x7FFFu + ((ua >> 16) & 1u)) >> 16;   // RNE
    ub = (ub + 0x7FFFu + ((ub >> 16) & 1u)) >> 16;
    return ua | (ub << 16);
}

__device__ __forceinline__ float bf_lo(unsigned int v) {
    return __builtin_bit_cast(float, v << 16);
}
__device__ __forceinline__ float bf_hi(unsigned int v) {
    return __builtin_bit_cast(float, v & 0xFFFF0000u);
}

// renorm W columns, emit Wbf[o][k] = bf16(W[o][k]*scale[k]) packed in pairs along k
__global__ void k_prep(const float* __restrict__ W, const int* __restrict__ eidx,
                       unsigned int* __restrict__ Wbf, int* __restrict__ flag) {
    __shared__ float s_scale[128];
    int t = threadIdx.x;  // 128 threads
    if (t < 64) {
        int v = eidx[2 * t + 1];
        unsigned long long m = __ballot(v == 0);
        if (t == 0) *flag = (m == ~0ull) ? 2 : 1;
    }
    float s = 0.f;
    for (int o = 0; o < CH; ++o) { float w = W[o * CH + t]; s += w * w; }
    s_scale[t] = (s > 1.0f) ? rsqrtf(s) : 1.0f;
    __syncthreads();
    // thread t = output row o
    for (int k16 = 0; k16 < 64; ++k16) {
        float a = W[t * CH + 2 * k16]     * s_scale[2 * k16];
        float b = W[t * CH + 2 * k16 + 1] * s_scale[2 * k16 + 1];
        Wbf[t * 64 + k16] = pack_bf16(a, b);
    }
}

// per-chunk bucket histogram (LDS, no global atomics)
__global__ __launch_bounds__(256) void k_part1(const int* __restrict__ eidx,
                                               const int* __restrict__ flag,
                                               int* __restrict__ cnt) {
    __shared__ int lc[256];
    int t = threadIdx.x, c = blockIdx.x;
    int st = *flag;
    lc[t] = 0;
    __syncthreads();
    long base = (long)c * CHUNK_E;
    #pragma unroll
    for (int i = 0; i < CHUNK_E / 256; ++i) {
        long e = base + i * 256 + t;
        if (e < N_EDGES) {
            int col = eidx[(size_t)st * (size_t)(N_EDGES + e)];
            atomicAdd(&lc[col >> 8], 1);
        }
    }
    __syncthreads();
    if (t < NB) cnt[c * NB + t] = lc[t];
}

// scan cnt -> absolute offsets per (chunk,bucket) + bstart
__global__ __launch_bounds__(256) void k_coff(const int* __restrict__ cnt,
                                              int* __restrict__ offs,
                                              int* __restrict__ bstart) {
    __shared__ int sh[256];
    int t = threadIdx.x;
    int run = 0;
    if (t < NB) {
        #pragma unroll 4
        for (int c = 0; c < NCHUNK; ++c) run += cnt[c * NB + t];
    }
    sh[t] = run;
    __syncthreads();
    for (int off = 1; off < 256; off <<= 1) {
        int u = (t >= off) ? sh[t - off] : 0;
        __syncthreads();
        sh[t] += u;
        __syncthreads();
    }
    int excl = sh[t] - run;
    if (t < NB) {
        bstart[t] = excl;
        if (t == NB - 1) bstart[NB] = excl + run;
        int base = excl;
        #pragma unroll 4
        for (int c = 0; c < NCHUNK; ++c) {
            offs[c * NB + t] = base;
            base += cnt[c * NB + t];
        }
    }
}

// scatter edges into bucket-partitioned ebuf (packed row:16 | colLow:8 << 16)
__global__ __launch_bounds__(256) void k_part2(const int* __restrict__ eidx,
                                               const int* __restrict__ flag,
                                               const int* __restrict__ offs,
                                               unsigned int* __restrict__ ebuf) {
    __shared__ int lcur[256];
    int t = threadIdx.x, c = blockIdx.x;
    int st = *flag;
    if (t < NB) lcur[t] = offs[c * NB + t];
    __syncthreads();
    long base = (long)c * CHUNK_E;
    #pragma unroll
    for (int i = 0; i < CHUNK_E / 256; ++i) {
        long e = base + i * 256 + t;
        if (e < N_EDGES) {
            int row = eidx[(size_t)st * (size_t)e];
            int col = eidx[(size_t)st * (size_t)(N_EDGES + e)];
            int pos = atomicAdd(&lcur[col >> 8], 1);
            ebuf[pos] = (unsigned int)(row & 0xFFFF) | ((unsigned int)(col & 255) << 16);
        }
    }
}

// per-bucket: histogram -> rowptr/dinv (fused), then exact scatter ebuf -> src
__global__ __launch_bounds__(256) void k_sort(const unsigned int* __restrict__ ebuf,
                                              const int* __restrict__ bstart,
                                              int* __restrict__ rowptr,
                                              float* __restrict__ dinv,
                                              int* __restrict__ src) {
    __shared__ int ldeg[256];
    __shared__ int lcur[256];
    __shared__ int sh[256];
    int t = threadIdx.x, b = blockIdx.x;
    int i0 = bstart[b], i1 = bstart[b + 1];
    ldeg[t] = 0;
    __syncthreads();
    for (int i = i0 + t; i < i1; i += 256) {
        unsigned int p = ebuf[i];
        atomicAdd(&ldeg[(p >> 16) & 255], 1);
    }
    __syncthreads();
    int d = ldeg[t];
    sh[t] = d;
    __syncthreads();
    for (int off = 1; off < 256; off <<= 1) {
        int u = (t >= off) ? sh[t - off] : 0;
        __syncthreads();
        sh[t] += u;
        __syncthreads();
    }
    int local_rp = i0 + sh[t] - d;
    int n = (b << 8) + t;
    if (n < N_NODES) {
        rowptr[n] = local_rp;
        dinv[n] = rsqrtf((float)(d + 1));
    }
    if (b == NB - 1 && t == 0) rowptr[N_NODES] = N_EDGES;
    lcur[t] = local_rp;
    __syncthreads();
    for (int i = i0 + t; i < i1; i += 256) {
        unsigned int p = ebuf[i];
        int pos = atomicAdd(&lcur[(p >> 16) & 255], 1);
        src[pos] = (int)(p & 0xFFFF);
    }
}

// MFMA GEMM: hs16 = bf16((x @ Wn^T) * dinv[row]).
// Block = 256 thr (4 waves), tile 64 rows x 128 cols; wave w: rows 16w..16w+15.
// LDS 16B chunks XOR-swizzled: chunk c16 of row r at r*16 + (c16 ^ (r&7)).
__global__ __launch_bounds__(256) void k_gemm(const float* __restrict__ x,
                                              const unsigned int* __restrict__ Wbf,
                                              const float* __restrict__ dinv,
                                              unsigned int* __restrict__ hs16) {
    __shared__ uint4 xs[64 * 16];    // 64 rows x 128 bf16 (16 KB)
    __shared__ uint4 wsl[128 * 16];  // 128 o-rows x 128 k bf16 (32 KB)
    int t = threadIdx.x;
    int base = blockIdx.x * 64;
    // stage x -> bf16 LDS (swizzled)
    #pragma unroll
    for (int it = 0; it < 4; ++it) {
        int idx = it * 256 + t;
        int r = idx >> 4, c16 = idx & 15;
        int n = base + r;
        float4 v0 = make_float4(0.f, 0.f, 0.f, 0.f), v1 = v0;
        if (n < N_NODES) {
            v0 = *(const float4*)&x[(size_t)n * CH + c16 * 8];
            v1 = *(const float4*)&x[(size_t)n * CH + c16 * 8 + 4];
        }
        uint4 p;
        p.x = pack_bf16(v0.x, v0.y); p.y = pack_bf16(v0.z, v0.w);
        p.z = pack_bf16(v1.x, v1.y); p.w = pack_bf16(v1.z, v1.w);
        xs[r * 16 + (c16 ^ (r & 7))] = p;
    }
    // stage Wbf -> LDS (swizzled)
    const uint4* wb4 = (const uint4*)Wbf;
    #pragma unroll
    for (int it = 0; it < 8; ++it) {
        int idx = it * 256 + t;
        int o = idx >> 4, c16 = idx & 15;
        wsl[o * 16 + (c16 ^ (o & 7))] = wb4[idx];
    }
    __syncthreads();
    int w = t >> 6, l = t & 63;
    int lrow = w * 16 + (l & 15);   // A row (local): also D col-index base l&15
    int hi = l >> 4;                // k-chunk / D row-group
    bf16x8 a[4];
    #pragma unroll
    for (int ks = 0; ks < 4; ++ks) {
        int c16 = ks * 4 + hi;
        a[ks] = __builtin_bit_cast(bf16x8, xs[lrow * 16 + (c16 ^ (lrow & 7))]);
    }
    float di[4];
    #pragma unroll
    for (int r = 0; r < 4; ++r) {
        int n = base + w * 16 + hi * 4 + r;
        di[r] = (n < N_NODES) ? dinv[n] : 0.f;
    }
    #pragma unroll
    for (int tc = 0; tc < 8; ++tc) {
        int col = tc * 16 + (l & 15);
        f32x4 acc = {0.f, 0.f, 0.f, 0.f};
        #pragma unroll
        for (int ks = 0; ks < 4; ++ks) {
            int c16 = ks * 4 + hi;
            bf16x8 bf = __builtin_bit_cast(bf16x8, wsl[col * 16 + (c16 ^ (col & 7))]);
            acc = __builtin_amdgcn_mfma_f32_16x16x32_bf16(a[ks], bf, acc, 0, 0, 0);
        }
        #pragma unroll
        for (int r = 0; r < 4; ++r) {
            float lo = acc[r] * di[r];
            float hv = __shfl_xor(lo, 1);   // partner holds col^1
            if ((l & 1) == 0) {
                int n = base + w * 16 + hi * 4 + r;
                if (n < N_NODES)
                    hs16[(size_t)n * 64 + (col >> 1)] = pack_bf16(lo, hv);
            }
        }
    }
}

// one wave per destination node; lane handles 2 channels (1 uint = 2 bf16)
__global__ __launch_bounds__(256) void k_gather(const int* __restrict__ rowptr,
                                                const int* __restrict__ src,
                                                const unsigned int* __restrict__ hs16,
                                                const float* __restrict__ dinv,
                                                const float* __restrict__ b,
                                                float* __restrict__ out) {
    int wid = threadIdx.x >> 6;
    int lane = threadIdx.x & 63;
    int n = blockIdx.x * 4 + wid;
    if (n >= N_NODES) return;
    int j = rowptr[n];
    int jend = rowptr[n + 1];
    float2 acc = make_float2(0.f, 0.f);
    for (; j + 8 <= jend; j += 8) {
        int r0 = src[j],     r1 = src[j + 1], r2 = src[j + 2], r3 = src[j + 3];
        int r4 = src[j + 4], r5 = src[j + 5], r6 = src[j + 6], r7 = src[j + 7];
        unsigned int v0 = hs16[(size_t)r0 * 64 + lane];
        unsigned int v1 = hs16[(size_t)r1 * 64 + lane];
        unsigned int v2 = hs16[(size_t)r2 * 64 + lane];
        unsigned int v3 = hs16[(size_t)r3 * 64 + lane];
        unsigned int v4 = hs16[(size_t)r4 * 64 + lane];
        unsigned int v5 = hs16[(size_t)r5 * 64 + lane];
        unsigned int v6 = hs16[(size_t)r6 * 64 + lane];
        unsigned int v7 = hs16[(size_t)r7 * 64 + lane];
        acc.x += ((bf_lo(v0) + bf_lo(v1)) + (bf_lo(v2) + bf_lo(v3)))
               + ((bf_lo(v4) + bf_lo(v5)) + (bf_lo(v6) + bf_lo(v7)));
        acc.y += ((bf_hi(v0) + bf_hi(v1)) + (bf_hi(v2) + bf_hi(v3)))
               + ((bf_hi(v4) + bf_hi(v5)) + (bf_hi(v6) + bf_hi(v7)));
    }
    for (; j < jend; ++j) {
        int r = src[j];
        unsigned int v = hs16[(size_t)r * 64 + lane];
        acc.x += bf_lo(v);
        acc.y += bf_hi(v);
    }
    float di = dinv[n];
    unsigned int sv = hs16[(size_t)n * 64 + lane];
    float2 bv = *(const float2*)&b[lane * 2];
    float2 o;
    o.x = (acc.x + bf_lo(sv)) * di + bv.x;
    o.y = (acc.y + bf_hi(sv)) * di + bv.y;
    *(float2*)&out[(size_t)n * CH + lane * 2] = o;
}

extern "C" void kernel_launch(void* const* d_in, const int* in_sizes, int n_in,
                              void* d_out, int out_size, void* d_ws, size_t ws_size,
                              hipStream_t stream) {
    const float* x = (const float*)d_in[0];
    const int* eidx = (const int*)d_in[1];
    const float* W = (const float*)d_in[2];
    const float* b = (const float*)d_in[3];
    float* out = (float*)d_out;

    char* ws = (char*)d_ws;
    unsigned int* Wbf    = (unsigned int*)(ws + WS_WBF);
    int*   flag          = (int*)(ws + WS_FLAG);
    int*   cnt           = (int*)(ws + WS_CNT);
    int*   offs          = (int*)(ws + WS_OFFS);
    int*   bstart        = (int*)(ws + WS_BSTART);
    int*   rowptr        = (int*)(ws + WS_ROWPTR);
    float* dinv          = (float*)(ws + WS_DINV);
    int*   srcarr        = (int*)(ws + WS_SRC);
    unsigned int* hs16   = (unsigned int*)(ws + WS_H);
    unsigned int* ebuf   = (unsigned int*)(ws + WS_H);  // alias: dead before k_gemm

    k_prep<<<1, 128, 0, stream>>>(W, eidx, Wbf, flag);
    k_part1<<<NCHUNK, 256, 0, stream>>>(eidx, flag, cnt);
    k_coff<<<1, 256, 0, stream>>>(cnt, offs, bstart);
    k_part2<<<NCHUNK, 256, 0, stream>>>(eidx, flag, offs, ebuf);
    k_sort<<<NB, 256, 0, stream>>>(ebuf, bstart, rowptr, dinv, srcarr);
    k_gemm<<<(N_NODES + 63) / 64, 256, 0, stream>>>(x, Wbf, dinv, hs16);
    k_gather<<<(N_NODES + 3) / 4, 256, 0, stream>>>(rowptr, srcarr, hs16, dinv, b, out);
}

// Round 7
// 119.090 us; speedup vs baseline: 12.0287x; 1.4127x over previous
//
#include <hip/hip_runtime.h>

#define N_NODES 50000
#define N_EDGES 1600000
#define CH 128
#define NB 196         // buckets of 256 nodes: bucket = col >> 8
#define CHUNK_E 2048
#define NCHUNK 784     // ceil(N_EDGES / CHUNK_E) = 782, padded to 784 (mult of 4)

// ws layout (bytes), total ~21 MB:
#define WS_WBF     0         // Wbf [128 o][64 words] bf16-pairs (renormed W, 32KB)
#define WS_CNT     32768     // cnt [NB][NCHUNK] int (614656)
#define WS_OFFS    647424    // offs [NB][NCHUNK] int (614656)
#define WS_BTOT    1262080   // btot [NB] int
#define WS_BSTART  1262864   // bstart [NB+1] int
#define WS_ROWPTR  1263656   // rowptr [N+1] int
#define WS_DINV    1463664   // dinv [N] f32
#define WS_SCL     1663664   // scl [N] f32 (per-row int8 scale)
#define WS_SRC     1863664   // src [E] int (6.4MB)
#define WS_EQ      8263664   // ebuf [E] u32 (sort input) ALIAS q8 [N][128] int8 (gemm out)
#define WS_ESTASH  14663664  // estash [E] u32 = row | col<<16 (6.4MB)

typedef __bf16 bf16x8 __attribute__((ext_vector_type(8)));
typedef float f32x4 __attribute__((ext_vector_type(4)));

__device__ __forceinline__ unsigned int pack_bf16(float a, float b) {
    unsigned int ua = __builtin_bit_cast(unsigned int, a);
    unsigned int ub = __builtin_bit_cast(unsigned int, b);
    ua = (ua + 0x7FFFu + ((ua >> 16) & 1u)) >> 16;   // RNE
    ub = (ub + 0x7FFFu + ((ub >> 16) & 1u)) >> 16;
    return ua | (ub << 16);
}

// renorm W columns, emit Wbf[o][k] = bf16(W[o][k]*scale[k]) packed in pairs along k
__global__ void k_prep(const float* __restrict__ W, unsigned int* __restrict__ Wbf) {
    __shared__ float s_scale[128];
    int t = threadIdx.x;  // 128 threads
    float s = 0.f;
    for (int o = 0; o < CH; ++o) { float w = W[o * CH + t]; s += w * w; }
    s_scale[t] = (s > 1.0f) ? rsqrtf(s) : 1.0f;
    __syncthreads();
    for (int k16 = 0; k16 < 64; ++k16) {
        float a = W[t * CH + 2 * k16]     * s_scale[2 * k16];
        float b = W[t * CH + 2 * k16 + 1] * s_scale[2 * k16 + 1];
        Wbf[t * 64 + k16] = pack_bf16(a, b);
    }
}

// pass 1 over edges: detect stride, stash packed (row|col<<16), bucket histogram
__global__ __launch_bounds__(256) void k_part1(const int* __restrict__ eidx,
                                               unsigned int* __restrict__ estash,
                                               int* __restrict__ cnt) {
    __shared__ int lc[256];
    __shared__ int s_st;
    int t = threadIdx.x, c = blockIdx.x;
    lc[t] = 0;
    if (t < 64) {
        int v = eidx[2 * t + 1];   // int64: zero high words; int32: random row vals
        unsigned long long m = __ballot(v == 0);
        if (t == 0) s_st = (m == ~0ull) ? 2 : 1;
    }
    __syncthreads();
    int st = s_st;
    long base = (long)c * CHUNK_E;
    #pragma unroll
    for (int i = 0; i < CHUNK_E / 256; ++i) {
        long e = base + i * 256 + t;
        if (e < N_EDGES) {
            int row = eidx[(size_t)st * (size_t)e];
            int col = eidx[(size_t)st * (size_t)(N_EDGES + e)];
            estash[e] = (unsigned int)row | ((unsigned int)col << 16);
            atomicAdd(&lc[col >> 8], 1);
        }
    }
    __syncthreads();
    if (t < NB) cnt[t * NCHUNK + c] = lc[t];
}

// per-bucket scan over chunks: offs[b][c] (relative excl) + btot[b]
__global__ __launch_bounds__(256) void k_coff1(const int* __restrict__ cnt,
                                               int* __restrict__ offs,
                                               int* __restrict__ btot) {
    __shared__ int sh[256];
    int t = threadIdx.x, b = blockIdx.x;
    const int4* cp = (const int4*)(cnt + b * NCHUNK);
    int4 v = make_int4(0, 0, 0, 0);
    if (t < NCHUNK / 4) v = cp[t];
    int s = v.x + v.y + v.z + v.w;
    sh[t] = s;
    __syncthreads();
    for (int off = 1; off < 256; off <<= 1) {
        int u = (t >= off) ? sh[t - off] : 0;
        __syncthreads();
        sh[t] += u;
        __syncthreads();
    }
    int base = sh[t] - s;  // exclusive
    if (t < NCHUNK / 4) {
        int4 o;
        o.x = base;
        o.y = o.x + v.x;
        o.z = o.y + v.y;
        o.w = o.z + v.z;
        ((int4*)(offs + b * NCHUNK))[t] = o;
    }
    if (t == 255) btot[b] = sh[255];
}

// scan bucket totals -> bstart
__global__ __launch_bounds__(256) void k_coff2(const int* __restrict__ btot,
                                               int* __restrict__ bstart) {
    __shared__ int sh[256];
    int t = threadIdx.x;
    int v = (t < NB) ? btot[t] : 0;
    sh[t] = v;
    __syncthreads();
    for (int off = 1; off < 256; off <<= 1) {
        int u = (t >= off) ? sh[t - off] : 0;
        __syncthreads();
        sh[t] += u;
        __syncthreads();
    }
    int excl = sh[t] - v;
    if (t < NB) bstart[t] = excl;
    if (t == NB - 1) bstart[NB] = excl + v;
}

// pass 2: scatter estash into bucket-partitioned ebuf (row:16 | colLow:8 << 16)
__global__ __launch_bounds__(256) void k_part2(const unsigned int* __restrict__ estash,
                                               const int* __restrict__ offs,
                                               const int* __restrict__ bstart,
                                               unsigned int* __restrict__ ebuf) {
    __shared__ int lcur[256];
    int t = threadIdx.x, c = blockIdx.x;
    if (t < NB) lcur[t] = bstart[t] + offs[t * NCHUNK + c];
    __syncthreads();
    long base = (long)c * CHUNK_E;
    #pragma unroll
    for (int i = 0; i < CHUNK_E / 256; ++i) {
        long e = base + i * 256 + t;
        if (e < N_EDGES) {
            unsigned int u = estash[e];
            int bb = u >> 24;   // col >> 8
            int pos = atomicAdd(&lcur[bb], 1);
            ebuf[pos] = (u & 0xFFFFu) | (((u >> 16) & 0xFFu) << 16);
        }
    }
}

// per-bucket: histogram -> rowptr/dinv (fused), then exact scatter ebuf -> src
__global__ __launch_bounds__(256) void k_sort(const unsigned int* __restrict__ ebuf,
                                              const int* __restrict__ bstart,
                                              int* __restrict__ rowptr,
                                              float* __restrict__ dinv,
                                              int* __restrict__ src) {
    __shared__ int ldeg[256];
    __shared__ int lcur[256];
    __shared__ int sh[256];
    int t = threadIdx.x, b = blockIdx.x;
    int i0 = bstart[b], i1 = bstart[b + 1];
    ldeg[t] = 0;
    __syncthreads();
    for (int i = i0 + t; i < i1; i += 256) {
        unsigned int p = ebuf[i];
        atomicAdd(&ldeg[(p >> 16) & 255], 1);
    }
    __syncthreads();
    int d = ldeg[t];
    sh[t] = d;
    __syncthreads();
    for (int off = 1; off < 256; off <<= 1) {
        int u = (t >= off) ? sh[t - off] : 0;
        __syncthreads();
        sh[t] += u;
        __syncthreads();
    }
    int local_rp = i0 + sh[t] - d;
    int n = (b << 8) + t;
    if (n < N_NODES) {
        rowptr[n] = local_rp;
        dinv[n] = rsqrtf((float)(d + 1));
    }
    if (b == NB - 1 && t == 0) rowptr[N_NODES] = N_EDGES;
    lcur[t] = local_rp;
    __syncthreads();
    for (int i = i0 + t; i < i1; i += 256) {
        unsigned int p = ebuf[i];
        int pos = atomicAdd(&lcur[(p >> 16) & 255], 1);
        src[pos] = (int)(p & 0xFFFFu);
    }
}

// MFMA GEMM + int8 quantize: q8[n] = int8(hs_n / scl[n]), scl[n] = rowmax/127,
// hs_n = (x_n @ Wn^T) * dinv[n]. Block = 4 waves, tile 64 rows x 128 cols.
__global__ __launch_bounds__(256) void k_gemm(const float* __restrict__ x,
                                              const unsigned int* __restrict__ Wbf,
                                              const float* __restrict__ dinv,
                                              unsigned int* __restrict__ q8,
                                              float* __restrict__ scl) {
    __shared__ uint4 SMEM[3072];          // 48KB: [0,1024)=xs, [1024,3072)=wsl
    uint4* xs = SMEM;                     // 64 rows x 128 bf16 (16 KB)
    uint4* wsl = SMEM + 1024;             // 128 o-rows x 128 k bf16 (32 KB)
    float* scratch = (float*)SMEM;        // epilogue: 64 x 132 f32 (33.8 KB)
    int t = threadIdx.x;
    int base = blockIdx.x * 64;
    // stage x -> bf16 LDS (swizzled 16B chunks)
    #pragma unroll
    for (int it = 0; it < 4; ++it) {
        int idx = it * 256 + t;
        int r = idx >> 4, c16 = idx & 15;
        int n = base + r;
        float4 v0 = make_float4(0.f, 0.f, 0.f, 0.f), v1 = v0;
        if (n < N_NODES) {
            v0 = *(const float4*)&x[(size_t)n * CH + c16 * 8];
            v1 = *(const float4*)&x[(size_t)n * CH + c16 * 8 + 4];
        }
        uint4 p;
        p.x = pack_bf16(v0.x, v0.y); p.y = pack_bf16(v0.z, v0.w);
        p.z = pack_bf16(v1.x, v1.y); p.w = pack_bf16(v1.z, v1.w);
        xs[r * 16 + (c16 ^ (r & 7))] = p;
    }
    const uint4* wb4 = (const uint4*)Wbf;
    #pragma unroll
    for (int it = 0; it < 8; ++it) {
        int idx = it * 256 + t;
        int o = idx >> 4, c16 = idx & 15;
        wsl[o * 16 + (c16 ^ (o & 7))] = wb4[idx];
    }
    __syncthreads();
    int w = t >> 6, l = t & 63;
    int lrow = w * 16 + (l & 15);
    int hi = l >> 4;
    bf16x8 a[4];
    #pragma unroll
    for (int ks = 0; ks < 4; ++ks) {
        int c16 = ks * 4 + hi;
        a[ks] = __builtin_bit_cast(bf16x8, xs[lrow * 16 + (c16 ^ (lrow & 7))]);
    }
    float di[4];
    #pragma unroll
    for (int r = 0; r < 4; ++r) {
        int n = base + w * 16 + hi * 4 + r;
        di[r] = (n < N_NODES) ? dinv[n] : 0.f;
    }
    float vals[8][4];
    #pragma unroll
    for (int tc = 0; tc < 8; ++tc) {
        int col = tc * 16 + (l & 15);
        f32x4 acc = {0.f, 0.f, 0.f, 0.f};
        #pragma unroll
        for (int ks = 0; ks < 4; ++ks) {
            int c16 = ks * 4 + hi;
            bf16x8 bf = __builtin_bit_cast(bf16x8, wsl[col * 16 + (c16 ^ (col & 7))]);
            acc = __builtin_amdgcn_mfma_f32_16x16x32_bf16(a[ks], bf, acc, 0, 0, 0);
        }
        #pragma unroll
        for (int r = 0; r < 4; ++r) vals[tc][r] = acc[r] * di[r];
    }
    __syncthreads();  // all wsl/xs reads done; safe to overwrite as scratch
    #pragma unroll
    for (int tc = 0; tc < 8; ++tc) {
        int col = tc * 16 + (l & 15);
        #pragma unroll
        for (int r = 0; r < 4; ++r) {
            int rl = w * 16 + hi * 4 + r;
            scratch[rl * 132 + col] = vals[tc][r];
        }
    }
    __syncthreads();
    // quantize: 4 threads per row, 32 cols each
    int rl = t >> 2, q = t & 3;
    const float4* rp = (const float4*)&scratch[rl * 132 + q * 32];
    float4 f[8];
    float m = 0.f;
    #pragma unroll
    for (int k = 0; k < 8; ++k) {
        f[k] = rp[k];
        m = fmaxf(m, fmaxf(fmaxf(fabsf(f[k].x), fabsf(f[k].y)),
                           fmaxf(fabsf(f[k].z), fabsf(f[k].w))));
    }
    m = fmaxf(m, __shfl_xor(m, 1));
    m = fmaxf(m, __shfl_xor(m, 2));
    float sc = m * (1.0f / 127.0f);
    float inv = (m > 0.f) ? (127.0f / m) : 0.f;
    int n = base + rl;
    if (n < N_NODES) {
        unsigned int u[8];
        #pragma unroll
        for (int k = 0; k < 8; ++k) {
            int b0 = __float2int_rn(f[k].x * inv);
            int b1 = __float2int_rn(f[k].y * inv);
            int b2 = __float2int_rn(f[k].z * inv);
            int b3 = __float2int_rn(f[k].w * inv);
            u[k] = (unsigned int)(b0 & 255) | ((unsigned int)(b1 & 255) << 8) |
                   ((unsigned int)(b2 & 255) << 16) | ((unsigned int)(b3 & 255) << 24);
        }
        uint4* qp = (uint4*)&q8[(size_t)n * 32 + q * 8];
        qp[0] = make_uint4(u[0], u[1], u[2], u[3]);
        qp[1] = make_uint4(u[4], u[5], u[6], u[7]);
        if (q == 0) scl[n] = sc;
    }
}

// wave per node; half-wave per edge (32 lanes x 4 int8 channels)
__global__ __launch_bounds__(256) void k_gather(const int* __restrict__ rowptr,
                                                const int* __restrict__ src,
                                                const unsigned int* __restrict__ q8,
                                                const float* __restrict__ scl,
                                                const float* __restrict__ dinv,
                                                const float* __restrict__ b,
                                                float* __restrict__ out) {
    int t = threadIdx.x;
    int wid = t >> 6, lane = t & 63;
    int half = lane >> 5, lc = lane & 31;
    int n = blockIdx.x * 4 + wid;
    if (n >= N_NODES) return;
    int j0 = rowptr[n], j1 = rowptr[n + 1];
    float a0 = 0.f, a1 = 0.f, a2 = 0.f, a3 = 0.f;
    int jj = j0;
    for (; jj + 8 <= j1; jj += 8) {
        #pragma unroll
        for (int k = 0; k < 4; ++k) {
            int r = src[jj + 2 * k + half];
            float sc = scl[r];
            unsigned int v = q8[(size_t)r * 32 + lc];
            a0 = fmaf((float)(signed char)(v), sc, a0);
            a1 = fmaf((float)(signed char)(v >> 8), sc, a1);
            a2 = fmaf((float)(signed char)(v >> 16), sc, a2);
            a3 = fmaf((float)(signed char)(v >> 24), sc, a3);
        }
    }
    for (; jj + 2 <= j1; jj += 2) {
        int r = src[jj + half];
        float sc = scl[r];
        unsigned int v = q8[(size_t)r * 32 + lc];
        a0 = fmaf((float)(signed char)(v), sc, a0);
        a1 = fmaf((float)(signed char)(v >> 8), sc, a1);
        a2 = fmaf((float)(signed char)(v >> 16), sc, a2);
        a3 = fmaf((float)(signed char)(v >> 24), sc, a3);
    }
    if (jj < j1 && half == 0) {
        int r = src[jj];
        float sc = scl[r];
        unsigned int v = q8[(size_t)r * 32 + lc];
        a0 = fmaf((float)(signed char)(v), sc, a0);
        a1 = fmaf((float)(signed char)(v >> 8), sc, a1);
        a2 = fmaf((float)(signed char)(v >> 16), sc, a2);
        a3 = fmaf((float)(signed char)(v >> 24), sc, a3);
    }
    a0 += __shfl_xor(a0, 32);
    a1 += __shfl_xor(a1, 32);
    a2 += __shfl_xor(a2, 32);
    a3 += __shfl_xor(a3, 32);
    if (half == 0) {
        float di = dinv[n];
        float sc = scl[n];
        unsigned int v = q8[(size_t)n * 32 + lc];
        float4 bv = *(const float4*)&b[4 * lc];
        float4 o;
        o.x = (a0 + (float)(signed char)(v) * sc) * di + bv.x;
        o.y = (a1 + (float)(signed char)(v >> 8) * sc) * di + bv.y;
        o.z = (a2 + (float)(signed char)(v >> 16) * sc) * di + bv.z;
        o.w = (a3 + (float)(signed char)(v >> 24) * sc) * di + bv.w;
        *(float4*)&out[(size_t)n * CH + 4 * lc] = o;
    }
}

extern "C" void kernel_launch(void* const* d_in, const int* in_sizes, int n_in,
                              void* d_out, int out_size, void* d_ws, size_t ws_size,
                              hipStream_t stream) {
    const float* x = (const float*)d_in[0];
    const int* eidx = (const int*)d_in[1];
    const float* W = (const float*)d_in[2];
    const float* b = (const float*)d_in[3];
    float* out = (float*)d_out;

    char* ws = (char*)d_ws;
    unsigned int* Wbf    = (unsigned int*)(ws + WS_WBF);
    int*   cnt           = (int*)(ws + WS_CNT);
    int*   offs          = (int*)(ws + WS_OFFS);
    int*   btot          = (int*)(ws + WS_BTOT);
    int*   bstart        = (int*)(ws + WS_BSTART);
    int*   rowptr        = (int*)(ws + WS_ROWPTR);
    float* dinv          = (float*)(ws + WS_DINV);
    float* sclp          = (float*)(ws + WS_SCL);
    int*   srcarr        = (int*)(ws + WS_SRC);
    unsigned int* ebuf   = (unsigned int*)(ws + WS_EQ);
    unsigned int* q8     = (unsigned int*)(ws + WS_EQ);  // alias: ebuf dead after k_sort
    unsigned int* estash = (unsigned int*)(ws + WS_ESTASH);

    k_prep<<<1, 128, 0, stream>>>(W, Wbf);
    k_part1<<<NCHUNK, 256, 0, stream>>>(eidx, estash, cnt);
    k_coff1<<<NB, 256, 0, stream>>>(cnt, offs, btot);
    k_coff2<<<1, 256, 0, stream>>>(btot, bstart);
    k_part2<<<NCHUNK, 256, 0, stream>>>(estash, offs, bstart, ebuf);
    k_sort<<<NB, 256, 0, stream>>>(ebuf, bstart, rowptr, dinv, srcarr);
    k_gemm<<<(N_NODES + 63) / 64, 256, 0, stream>>>(x, Wbf, dinv, q8, sclp);
    k_gather<<<(N_NODES + 3) / 4, 256, 0, stream>>>(rowptr, srcarr, q8, sclp, dinv, b, out);
}